// Round 1
// baseline (82386.328 us; speedup 1.0000x reference)
//
#include <hip/hip_runtime.h>
#include <hip/hip_cooperative_groups.h>

namespace cg = cooperative_groups;

// Problem constants (fixed by the reference)
#define BATCH 256
#define TLEN  1000
#define HDIM  512
#define NG    8     // batch groups
#define GB    32    // batches per group
#define NS    32    // column slices
#define SC    16    // columns per slice
#define WPAD  516   // padded k-stride for LDS weight tiles (breaks bank conflicts)

// 256 blocks x 512 threads, cooperative (2 grid syncs per time step).
// Block (g,s): batch group g (32 batches) x column slice s (16 cols).
// Thread (i,j): one (batch, col) cell. h for own cell persists in a register.
// Weights column-slice lives in LDS fp32 (3 x 16 x 516 x 4B ~= 97 KB), staged once.
__launch_bounds__(512, 1)
__global__ void mc_gru_kernel(
    const float* __restrict__ inputs,  // (B, T)  [IN==1]
    const float* __restrict__ St,      // (B)
    const float* __restrict__ Mass,    // (B)
    const float* __restrict__ Wz,      // (513, 512) row-major
    const float* __restrict__ bz,      // (512)
    const float* __restrict__ Wr,      // (513, 512)
    const float* __restrict__ br,      // (512)
    const float* __restrict__ Wh,      // (515, 512)
    const float* __restrict__ bh,      // (512)
    const float* __restrict__ Wk,      // (513)
    const float* __restrict__ bk,      // (1)
    float* __restrict__ out,           // (B, T, H)
    float* __restrict__ h_buf,         // (B, H)   exchange: h_{t-1}
    float* __restrict__ hr_buf,        // (B, H)   exchange: h*r
    float* __restrict__ kpart)         // (B, NS)  per-slice partials of h.Wk
{
    __shared__ float wz_l[SC * WPAD];
    __shared__ float wr_l[SC * WPAD];
    __shared__ float wh_l[SC * WPAD];
    __shared__ float wz0[SC], wr0[SC], wh0[SC], wh513[SC], wh514[SC];
    __shared__ float bz_l[SC], br_l[SC], bh_l[SC], wk_l[SC];
    __shared__ float st_l[GB], mass_l[GB];
    __shared__ float k_lds[GB];        // k carry per batch (tracked redundantly per block)

    const int tid = threadIdx.x;
    const int blk = blockIdx.x;
    const int g   = blk >> 5;          // batch group 0..7
    const int s   = blk & 31;          // column slice 0..31
    const int j   = tid & 15;          // col within slice
    const int i   = tid >> 4;          // batch within group 0..31
    const int bi  = g * GB + i;        // global batch
    const int col = s * SC + j;        // global column

    // ---- one-time staging: weight column-slice (rows 1..512 -> k-major per col) ----
    for (int idx = tid; idx < SC * HDIM; idx += 512) {
        int k  = idx >> 4;             // 0..511
        int jj = idx & 15;
        int c  = s * SC + jj;
        wz_l[jj * WPAD + k] = Wz[(1 + k) * HDIM + c];
        wr_l[jj * WPAD + k] = Wr[(1 + k) * HDIM + c];
        wh_l[jj * WPAD + k] = Wh[(1 + k) * HDIM + c];
    }
    if (tid < SC) {
        int c = s * SC + tid;
        wz0[tid]   = Wz[c];
        wr0[tid]   = Wr[c];
        wh0[tid]   = Wh[c];
        wh513[tid] = Wh[513 * HDIM + c];
        wh514[tid] = Wh[514 * HDIM + c];
        bz_l[tid]  = bz[c];
        br_l[tid]  = br[c];
        bh_l[tid]  = bh[c];
        wk_l[tid]  = Wk[c];
    }
    if (tid < GB) {
        st_l[tid]   = St[g * GB + tid];
        mass_l[tid] = Mass[g * GB + tid];
        k_lds[tid]  = 0.0f;            // k carry starts at 0
    }
    // zero the h exchange buffer (d_ws is poisoned 0xAA before every launch)
    h_buf[blk * HDIM + tid] = 0.0f;    // block blk zeroes batch row blk
    __syncthreads();

    const float wk512 = Wk[512];
    const float bk0   = bk[0];

    cg::grid_group grid = cg::this_grid();
    grid.sync();                        // h_buf zeroed everywhere

    float h_reg = 0.0f;                 // own (bi, col) element of h
    const float st_i   = st_l[i];
    const float mass_i = mass_l[i];
    const float* xrow  = inputs + bi * TLEN;
    const float* hrow  = h_buf  + bi * HDIM;
    const float* hrrow = hr_buf + bi * HDIM;

    for (int t = 0; t < TLEN; ++t) {
        const float x = xrow[t];

        // ---------- phase A: z, r gates (need full h_{t-1}) ----------
        float az = x * wz0[j];
        float ar = x * wr0[j];
        const float4* h4 = (const float4*)hrow;
        #pragma unroll 4
        for (int k4 = 0; k4 < HDIM / 4; ++k4) {
            float4 hv  = h4[k4];
            float4 wz4 = *(const float4*)&wz_l[j * WPAD + 4 * k4];
            float4 wr4 = *(const float4*)&wr_l[j * WPAD + 4 * k4];
            az += hv.x * wz4.x + hv.y * wz4.y + hv.z * wz4.z + hv.w * wz4.w;
            ar += hv.x * wr4.x + hv.y * wr4.y + hv.z * wr4.z + hv.w * wr4.w;
        }
        const float z = 1.0f / (1.0f + __expf(-(az + bz_l[j])));
        const float r = 1.0f / (1.0f + __expf(-(ar + br_l[j])));
        hr_buf[bi * HDIM + col] = h_reg * r;

        grid.sync();                    // h*r fully published

        // ---------- phase B: k carry, candidate, state update ----------
        if (tid < GB) {
            float c;
            if (t == 0) {
                c = 0.0f;               // reference k0 = 0
            } else {
                const float* kp = kpart + (g * GB + tid) * NS;
                float sum = 0.0f;
                #pragma unroll
                for (int q = 0; q < NS; ++q) sum += kp[q];
                c = 1.0f / (1.0f + __expf(-(sum + wk512 * k_lds[tid] + bk0)));
            }
            k_lds[tid] = c;
        }
        __syncthreads();
        const float kv = k_lds[i];

        float ah = x * wh0[j] + (st_i * kv) * wh513[j] + mass_i * wh514[j] + bh_l[j];
        const float4* hr4 = (const float4*)hrrow;
        #pragma unroll 4
        for (int k4 = 0; k4 < HDIM / 4; ++k4) {
            float4 hv  = hr4[k4];
            float4 wh4 = *(const float4*)&wh_l[j * WPAD + 4 * k4];
            ah += hv.x * wh4.x + hv.y * wh4.y + hv.z * wh4.z + hv.w * wh4.w;
        }
        const float e  = __expf(-2.0f * ah);
        const float ht = (1.0f - e) / (1.0f + e);     // tanh
        const float hn = (1.0f - z) * h_reg + z * ht;
        h_reg = hn;

        h_buf[bi * HDIM + col]          = hn;         // publish for next step
        out[(bi * TLEN + t) * HDIM + col] = hn;       // stream result

        // per-slice partial of h_new . Wk (reduce over the 16 j-lanes)
        float kc = hn * wk_l[j];
        kc += __shfl_xor(kc, 1);
        kc += __shfl_xor(kc, 2);
        kc += __shfl_xor(kc, 4);
        kc += __shfl_xor(kc, 8);
        if (j == 0) kpart[bi * NS + s] = kc;

        grid.sync();                    // h_new + kpart fully published
    }
}

extern "C" void kernel_launch(void* const* d_in, const int* in_sizes, int n_in,
                              void* d_out, int out_size, void* d_ws, size_t ws_size,
                              hipStream_t stream) {
    (void)in_sizes; (void)n_in; (void)out_size; (void)ws_size;

    const float* inputs = (const float*)d_in[0];
    const float* St     = (const float*)d_in[1];
    const float* Mass   = (const float*)d_in[2];
    const float* Wz     = (const float*)d_in[3];
    const float* bz     = (const float*)d_in[4];
    const float* Wr     = (const float*)d_in[5];
    const float* br     = (const float*)d_in[6];
    const float* Wh     = (const float*)d_in[7];
    const float* bh     = (const float*)d_in[8];
    const float* Wk     = (const float*)d_in[9];
    const float* bk     = (const float*)d_in[10];
    float* out = (float*)d_out;

    float* h_buf  = (float*)d_ws;                 // 256*512 f32 = 512 KB
    float* hr_buf = h_buf  + BATCH * HDIM;        // 512 KB
    float* kpart  = hr_buf + BATCH * HDIM;        // 256*32 f32 = 32 KB

    void* args[] = {
        (void*)&inputs, (void*)&St, (void*)&Mass,
        (void*)&Wz, (void*)&bz, (void*)&Wr, (void*)&br,
        (void*)&Wh, (void*)&bh, (void*)&Wk, (void*)&bk,
        (void*)&out, (void*)&h_buf, (void*)&hr_buf, (void*)&kpart
    };
    hipLaunchCooperativeKernel((const void*)mc_gru_kernel,
                               dim3(256), dim3(512), args, 0, stream);
}